// Round 6
// baseline (442.539 us; speedup 1.0000x reference)
//
#include <hip/hip_runtime.h>

#define SXD 256
#define SYD 256
#define SZD 32
#define NTOTAL (4 * SXD * SYD * SZD)      // 8388608 cells
#define TABLE_BYTES ((size_t)NTOTAL * sizeof(int))
#define CIN 32
#define COUT 32
#define WT4_FLOATS (27 * 8 * 32 * 4)      // 27648 floats, 110 KB

// wt4[((k*8 + ci2)*32 + co)*4 + j] = w[co][ci2*4+j][k]   (w is (COUT,CIN,27) flat)
// lane `co` loads one float4 = weights for 4 consecutive ci at its co.
__global__ __launch_bounds__(256) void wt4_kernel(const float* __restrict__ w,
                                                  float* __restrict__ wt4) {
    int t = blockIdx.x * 256 + threadIdx.x;
    if (t >= WT4_FLOATS) return;
    int j   = t & 3;
    int co  = (t >> 2) & 31;
    int ci2 = (t >> 7) & 7;
    int k   = t >> 10;
    wt4[t] = w[(co * CIN + (ci2 * 4 + j)) * 27 + k];
}

__global__ __launch_bounds__(256) void scatter_kernel(const int* __restrict__ idx,
                                                      int* __restrict__ table, int n) {
    int i = blockIdx.x * 256 + threadIdx.x;
    if (i >= n) return;
    int b = idx[4 * i + 0];
    int x = idx[4 * i + 1];
    int y = idx[4 * i + 2];
    int z = idx[4 * i + 3];
    table[((b * SXD + x) * SYD + y) * SZD + z] = i;
}

// Fused probe + conv. Wave = 2 points (half-wave each, lane = co).
// Probe: lane co probes offset co (co<27) -> all 27 probes in ONE parallel round.
// Match loop: 2 matches per iteration, all 32 float4 loads issued independently,
// 4 accumulator chains.
__global__ __launch_bounds__(256) void conv3_kernel(
    const float* __restrict__ f, const int* __restrict__ idx,
    const float* __restrict__ wt4, const float* __restrict__ bias,
    const int* __restrict__ table, float* __restrict__ out, int n) {
    int wave = blockIdx.x * 4 + (threadIdx.x >> 6);
    int lane = threadIdx.x & 63;
    int half = lane >> 5;
    int co   = lane & 31;
    int p    = wave * 2 + half;
    bool valid = p < n;

    int m = -1;
    if (valid) {
        int4 c = ((const int4*)idx)[p];            // b,x,y,z (broadcast per half)
        if (co < 27) {
            int dx = co / 9 - 1;
            int dy = (co / 3) % 3 - 1;
            int dz = co % 3 - 1;
            int nx = c.y + dx, ny = c.z + dy, nz = c.w + dz;
            if ((unsigned)nx < SXD && (unsigned)ny < SYD && (unsigned)nz < SZD)
                m = table[((c.x * SXD + nx) * SYD + ny) * SZD + nz];
        }
    }
    unsigned long long ball = __ballot(m >= 0);
    unsigned mymask = (unsigned)(ball >> (half * 32));   // uniform within half-wave

    float a0 = valid ? bias[co] : 0.0f;
    float a1 = 0.0f, a2 = 0.0f, a3 = 0.0f;

    while (mymask) {
        int k1 = __ffs(mymask) - 1; mymask &= mymask - 1;
        int k2 = -1;
        if (mymask) { k2 = __ffs(mymask) - 1; mymask &= mymask - 1; }

        int nbr1 = __shfl(m, (half << 5) + k1, 64);
        const float4* fr1 = (const float4*)(f + (size_t)nbr1 * CIN);
        const float4* wr1 = (const float4*)wt4 + k1 * 256 + co;
        float4 F1[8], W1[8];
#pragma unroll
        for (int q = 0; q < 8; ++q) { F1[q] = fr1[q]; W1[q] = wr1[q * 32]; }

        if (k2 >= 0) {   // k2 uniform per half-wave
            int nbr2 = __shfl(m, (half << 5) + k2, 64);
            const float4* fr2 = (const float4*)(f + (size_t)nbr2 * CIN);
            const float4* wr2 = (const float4*)wt4 + k2 * 256 + co;
            float4 F2[8], W2[8];
#pragma unroll
            for (int q = 0; q < 8; ++q) { F2[q] = fr2[q]; W2[q] = wr2[q * 32]; }
#pragma unroll
            for (int q = 0; q < 4; ++q) {
                a2 += F2[q].x * W2[q].x + F2[q].y * W2[q].y
                    + F2[q].z * W2[q].z + F2[q].w * W2[q].w;
                a3 += F2[q + 4].x * W2[q + 4].x + F2[q + 4].y * W2[q + 4].y
                    + F2[q + 4].z * W2[q + 4].z + F2[q + 4].w * W2[q + 4].w;
            }
        }
#pragma unroll
        for (int q = 0; q < 4; ++q) {
            a0 += F1[q].x * W1[q].x + F1[q].y * W1[q].y
                + F1[q].z * W1[q].z + F1[q].w * W1[q].w;
            a1 += F1[q + 4].x * W1[q + 4].x + F1[q + 4].y * W1[q + 4].y
                + F1[q + 4].z * W1[q + 4].z + F1[q + 4].w * W1[q + 4].w;
        }
    }
    if (valid) out[(size_t)p * COUT + co] = (a0 + a1) + (a2 + a3);
}

extern "C" void kernel_launch(void* const* d_in, const int* in_sizes, int n_in,
                              void* d_out, int out_size, void* d_ws, size_t ws_size,
                              hipStream_t stream) {
    const float* f    = (const float*)d_in[0];
    const int* idx    = (const int*)d_in[1];
    const float* w    = (const float*)d_in[2];
    const float* bias = (const float*)d_in[3];
    float* out        = (float*)d_out;
    int n = in_sizes[0] / CIN;  // 400000

    int*   table = (int*)d_ws;
    float* wt4   = (float*)((char*)d_ws + TABLE_BYTES);

    // ws is re-poisoned before every launch: rebuild table each call.
    hipMemsetAsync(table, 0xFF, TABLE_BYTES, stream);
    wt4_kernel<<<(WT4_FLOATS + 255) / 256, 256, 0, stream>>>(w, wt4);
    scatter_kernel<<<(n + 255) / 256, 256, 0, stream>>>(idx, table, n);
    conv3_kernel<<<(n + 7) / 8, 256, 0, stream>>>(f, idx, wt4, bias, table, out, n);
}